// Round 3
// baseline (359.467 us; speedup 1.0000x reference)
//
#include <hip/hip_runtime.h>
#include <hip/hip_cooperative_groups.h>

namespace cg = cooperative_groups;

#define N_NODES 100000
#define N_EDGES 640000
#define HIDDEN  128
#define EPS     1e-6f
#define NUM_CU  256

// Single cooperative kernel:
//   Phase 0: per-block redundant u,v,c  (u=att_w[0:128]@W, v=att_w[128:256]@W)
//   Phase 1: p_i=u.x_i, q_i=v.x_i, nacc_i=0   (grid-stride, 2 nodes/wave)
//   -- grid.sync --
//   Phase 2: a_e=exp(lrelu(p[src]+q[dst]+c)), atomicAdd nacc[dst]
//   -- grid.sync --
//   Phase 3: y=relu(x/n')+x; out = norm_w*y*rsqrt(mean(y^2)+eps)+norm_b
__global__ __launch_bounds__(256, 4)
void fused_gat(const float* __restrict__ x,
               const float* __restrict__ W,
               const float* __restrict__ b,
               const float* __restrict__ att_w,
               const float* __restrict__ norm_w,
               const float* __restrict__ norm_b,
               const int*   __restrict__ e,
               float* __restrict__ out,
               float* __restrict__ p,
               float* __restrict__ q,
               float* __restrict__ nacc) {
    __shared__ float su_s[2][HIDDEN];
    __shared__ float sv_s[2][HIDDEN];
    __shared__ float u_s[HIDDEN];
    __shared__ float v_s[HIDDEN];
    __shared__ float c_s;

    const int tid = threadIdx.x;
    const int k = tid & 127;
    const int h128 = tid >> 7;          // 0..1: which half of the j-range

    // ---- Phase 0: redundant per-block u,v (W is 64KB, L2-resident) ----
    {
        float su = 0.f, sv = 0.f;
        #pragma unroll 8
        for (int jj = 0; jj < 64; ++jj) {
            int j = h128 * 64 + jj;
            float w = W[j * HIDDEN + k];
            su += att_w[j] * w;
            sv += att_w[HIDDEN + j] * w;
        }
        su_s[h128][k] = su;
        sv_s[h128][k] = sv;
    }
    __syncthreads();
    if (tid < 128) {
        u_s[k] = su_s[0][k] + su_s[1][k];
        v_s[k] = sv_s[0][k] + sv_s[1][k];
    } else if (tid < 192) {             // wave 2: c = att_w.[b;b]
        int l = tid - 128;
        float t = att_w[l] * b[l] + att_w[HIDDEN + l] * b[l]
                + att_w[l + 64] * b[l + 64] + att_w[HIDDEN + l + 64] * b[l + 64];
        #pragma unroll
        for (int off = 32; off > 0; off >>= 1) t += __shfl_xor(t, off);
        if (l == 0) c_s = t;
    }
    __syncthreads();

    cg::grid_group grid = cg::this_grid();

    const int gwave  = (int)((blockIdx.x * blockDim.x + tid) >> 6);
    const int nwaves = (int)((gridDim.x * blockDim.x) >> 6);
    const int lane   = tid & 63;
    const int halfw  = lane >> 5;       // which node of the wave's pair
    const int sub    = lane & 31;       // float4 slot within the 128-row

    const float4 uv = ((const float4*)u_s)[sub];
    const float4 vv = ((const float4*)v_s)[sub];

    // ---- Phase 1: p, q, nacc=0 (2 nodes per wave per iteration) ----
    for (int node = gwave * 2 + halfw; node < N_NODES; node += nwaves * 2) {
        float4 xv = ((const float4*)(x + (size_t)node * HIDDEN))[sub];
        float sp = xv.x * uv.x + xv.y * uv.y + xv.z * uv.z + xv.w * uv.w;
        float sq = xv.x * vv.x + xv.y * vv.y + xv.z * vv.z + xv.w * vv.w;
        #pragma unroll
        for (int off = 16; off > 0; off >>= 1) {
            sp += __shfl_xor(sp, off);
            sq += __shfl_xor(sq, off);
        }
        if (sub == 0) {
            p[node] = sp;
            q[node] = sq;
            nacc[node] = 0.f;
        }
    }

    grid.sync();

    // ---- Phase 2: edge scores + atomic accumulate ----
    {
        const float c = c_s;
        const int nthreads = (int)(gridDim.x * blockDim.x);
        for (int eid = (int)(blockIdx.x * blockDim.x) + tid; eid < N_EDGES; eid += nthreads) {
            int2 ed = ((const int2*)e)[eid];          // (src, dst)
            float score = p[ed.x] + q[ed.y] + c;
            float lr = score > 0.f ? score : 0.2f * score;
            atomicAdd(&nacc[ed.y], expf(lr));
        }
    }

    grid.sync();

    // ---- Phase 3: relu/residual/RMSNorm ----
    {
        const float4 wv = ((const float4*)norm_w)[sub];
        const float4 bv = ((const float4*)norm_b)[sub];
        for (int node = gwave * 2 + halfw; node < N_NODES; node += nwaves * 2) {
            float nn = nacc[node];
            float inv_n = 1.f / (nn == 0.f ? 1.f : nn);
            float4 xv = ((const float4*)(x + (size_t)node * HIDDEN))[sub];
            float4 y;
            float h;
            h = xv.x * inv_n; h = h > 0.f ? h : 0.f; y.x = h + xv.x;
            h = xv.y * inv_n; h = h > 0.f ? h : 0.f; y.y = h + xv.y;
            h = xv.z * inv_n; h = h > 0.f ? h : 0.f; y.z = h + xv.z;
            h = xv.w * inv_n; h = h > 0.f ? h : 0.f; y.w = h + xv.w;

            float ss = y.x * y.x + y.y * y.y + y.z * y.z + y.w * y.w;
            #pragma unroll
            for (int off = 16; off > 0; off >>= 1) ss += __shfl_xor(ss, off);
            float inv_rms = rsqrtf(ss * (1.f / HIDDEN) + EPS);

            float4 ov;
            ov.x = wv.x * (y.x * inv_rms) + bv.x;
            ov.y = wv.y * (y.y * inv_rms) + bv.y;
            ov.z = wv.z * (y.z * inv_rms) + bv.z;
            ov.w = wv.w * (y.w * inv_rms) + bv.w;
            ((float4*)(out + (size_t)node * HIDDEN))[sub] = ov;
        }
    }
}

extern "C" void kernel_launch(void* const* d_in, const int* in_sizes, int n_in,
                              void* d_out, int out_size, void* d_ws, size_t ws_size,
                              hipStream_t stream) {
    const float* x      = (const float*)d_in[0];
    const float* W      = (const float*)d_in[1];
    const float* b      = (const float*)d_in[2];
    const float* att_w  = (const float*)d_in[3];
    const float* norm_w = (const float*)d_in[4];
    const float* norm_b = (const float*)d_in[5];
    const int*   e      = (const int*)d_in[6];
    float* out = (float*)d_out;

    // workspace layout (floats): p[N] q[N] nacc[N]
    float* ws   = (float*)d_ws;
    float* p    = ws;
    float* q    = p + N_NODES;
    float* nacc = q + N_NODES;

    int maxBlocksPerCU = 0;
    hipOccupancyMaxActiveBlocksPerMultiprocessor(&maxBlocksPerCU,
                                                 (const void*)fused_gat, 256, 0);
    if (maxBlocksPerCU < 1) maxBlocksPerCU = 1;
    int nblocks = maxBlocksPerCU * NUM_CU;
    if (nblocks > 1024) nblocks = 1024;

    void* args[] = {
        (void*)&x, (void*)&W, (void*)&b, (void*)&att_w,
        (void*)&norm_w, (void*)&norm_b, (void*)&e,
        (void*)&out, (void*)&p, (void*)&q, (void*)&nacc
    };
    hipLaunchCooperativeKernel((const void*)fused_gat,
                               dim3(nblocks), dim3(256),
                               args, 0, stream);
}

// Round 4
// 166.095 us; speedup vs baseline: 2.1642x; 2.1642x over previous
//
#include <hip/hip_runtime.h>

#define N_NODES 100000
#define N_EDGES 640000
#define HIDDEN  128
#define EPS     1e-6f

// ---------------------------------------------------------------------------
// Kernel A: per-block redundant u,v (64KB W is L2-resident; only 1024 blocks
// so aggregate redundant traffic ~64MB L2 ~ 2us), then grid-stride
// p_i = u.x_i, q_i = v.x_i, nacc_i = 0.  Block 0 also writes c.
// 2 nodes per wave, float4 (16B) per lane -> 1 KiB contiguous per wave.
// ---------------------------------------------------------------------------
__global__ __launch_bounds__(256, 4)
void node_pass(const float* __restrict__ x,
               const float* __restrict__ W,
               const float* __restrict__ b,
               const float* __restrict__ att_w,
               float* __restrict__ p,
               float* __restrict__ q,
               float* __restrict__ nacc,
               float* __restrict__ c_out) {
    __shared__ float su_s[2][HIDDEN];
    __shared__ float sv_s[2][HIDDEN];
    __shared__ float u_s[HIDDEN];
    __shared__ float v_s[HIDDEN];

    const int tid = threadIdx.x;
    const int k   = tid & 127;
    const int h   = tid >> 7;           // 0..1: half of the j-range

    // redundant u,v prologue (all co-resident blocks pay it concurrently)
    {
        float su = 0.f, sv = 0.f;
        #pragma unroll 8
        for (int jj = 0; jj < 64; ++jj) {
            int j = h * 64 + jj;
            float w = W[j * HIDDEN + k];
            su += att_w[j] * w;
            sv += att_w[HIDDEN + j] * w;
        }
        su_s[h][k] = su;
        sv_s[h][k] = sv;
    }
    __syncthreads();
    if (tid < 128) {
        u_s[k] = su_s[0][k] + su_s[1][k];
        v_s[k] = sv_s[0][k] + sv_s[1][k];
    } else if (tid < 192 && blockIdx.x == 0) {   // c: one wave of block 0
        int l = tid - 128;
        float t = att_w[l] * b[l] + att_w[HIDDEN + l] * b[l]
                + att_w[l + 64] * b[l + 64] + att_w[HIDDEN + l + 64] * b[l + 64];
        #pragma unroll
        for (int off = 32; off > 0; off >>= 1) t += __shfl_xor(t, off);
        if (l == 0) *c_out = t;
    }
    __syncthreads();

    const int gwave  = (int)((blockIdx.x * blockDim.x + tid) >> 6);
    const int nwaves = (int)((gridDim.x * blockDim.x) >> 6);
    const int lane   = tid & 63;
    const int halfw  = lane >> 5;
    const int sub    = lane & 31;

    const float4 uv = ((const float4*)u_s)[sub];
    const float4 vv = ((const float4*)v_s)[sub];

    for (int node = gwave * 2 + halfw; node < N_NODES; node += nwaves * 2) {
        float4 xv = ((const float4*)(x + (size_t)node * HIDDEN))[sub];
        float sp = xv.x * uv.x + xv.y * uv.y + xv.z * uv.z + xv.w * uv.w;
        float sq = xv.x * vv.x + xv.y * vv.y + xv.z * vv.z + xv.w * vv.w;
        #pragma unroll
        for (int off = 16; off > 0; off >>= 1) {
            sp += __shfl_xor(sp, off);
            sq += __shfl_xor(sq, off);
        }
        if (sub == 0) {
            p[node]    = sp;
            q[node]    = sq;
            nacc[node] = 0.f;
        }
    }
}

// ---------------------------------------------------------------------------
// Kernel B: 2 edges per thread (int4 load), a_e = exp(lrelu(p[src]+q[dst]+c)),
// atomicAdd into nacc[dst]. p/q/nacc ~400KB each -> L2/L3 resident.
// ---------------------------------------------------------------------------
__global__ void edge_kernel(const int* __restrict__ e,
                            const float* __restrict__ p,
                            const float* __restrict__ q,
                            const float* __restrict__ c,
                            float* __restrict__ nacc) {
    int t = blockIdx.x * blockDim.x + threadIdx.x;
    if (t * 2 >= N_EDGES) return;
    int4 ed = ((const int4*)e)[t];       // (src0,dst0,src1,dst1)
    float cc = c[0];
    float s0 = p[ed.x] + q[ed.y] + cc;
    float s1 = p[ed.z] + q[ed.w] + cc;
    s0 = s0 > 0.f ? s0 : 0.2f * s0;
    s1 = s1 > 0.f ? s1 : 0.2f * s1;
    atomicAdd(&nacc[ed.y], __expf(s0));
    atomicAdd(&nacc[ed.w], __expf(s1));
}

// ---------------------------------------------------------------------------
// Kernel C: y = relu(x/n') + x ; out = norm_w * y * rsqrt(mean(y^2)+eps) + norm_b
// 2 nodes per wave, float4 per lane.
// ---------------------------------------------------------------------------
__global__ void final_kernel(const float* __restrict__ x,
                             const float* __restrict__ nacc,
                             const float* __restrict__ norm_w,
                             const float* __restrict__ norm_b,
                             float* __restrict__ out) {
    int gid  = blockIdx.x * blockDim.x + threadIdx.x;
    int wave = gid >> 6;
    int lane = threadIdx.x & 63;
    int halfw = lane >> 5;
    int sub  = lane & 31;
    int node = wave * 2 + halfw;
    if (node >= N_NODES) return;

    float nn = nacc[node];
    float inv_n = 1.f / (nn == 0.f ? 1.f : nn);

    float4 xv = ((const float4*)(x + (size_t)node * HIDDEN))[sub];
    float4 y;
    float h;
    h = xv.x * inv_n; h = h > 0.f ? h : 0.f; y.x = h + xv.x;
    h = xv.y * inv_n; h = h > 0.f ? h : 0.f; y.y = h + xv.y;
    h = xv.z * inv_n; h = h > 0.f ? h : 0.f; y.z = h + xv.z;
    h = xv.w * inv_n; h = h > 0.f ? h : 0.f; y.w = h + xv.w;

    float ss = y.x * y.x + y.y * y.y + y.z * y.z + y.w * y.w;
    #pragma unroll
    for (int off = 16; off > 0; off >>= 1) ss += __shfl_xor(ss, off);
    float inv_rms = rsqrtf(ss * (1.f / HIDDEN) + EPS);

    float4 wv = ((const float4*)norm_w)[sub];
    float4 bv = ((const float4*)norm_b)[sub];
    float4 ov;
    ov.x = wv.x * (y.x * inv_rms) + bv.x;
    ov.y = wv.y * (y.y * inv_rms) + bv.y;
    ov.z = wv.z * (y.z * inv_rms) + bv.z;
    ov.w = wv.w * (y.w * inv_rms) + bv.w;
    ((float4*)(out + (size_t)node * HIDDEN))[sub] = ov;
}

extern "C" void kernel_launch(void* const* d_in, const int* in_sizes, int n_in,
                              void* d_out, int out_size, void* d_ws, size_t ws_size,
                              hipStream_t stream) {
    const float* x      = (const float*)d_in[0];
    const float* W      = (const float*)d_in[1];
    const float* b      = (const float*)d_in[2];
    const float* att_w  = (const float*)d_in[3];
    const float* norm_w = (const float*)d_in[4];
    const float* norm_b = (const float*)d_in[5];
    const int*   e      = (const int*)d_in[6];
    float* out = (float*)d_out;

    // workspace layout (floats): p[N] q[N] nacc[N] c[1]
    float* ws   = (float*)d_ws;
    float* p    = ws;
    float* q    = p + N_NODES;
    float* nacc = q + N_NODES;
    float* c    = nacc + N_NODES;

    // A: 1024 grid-stride blocks (4/CU x 256 CUs), fused uvc + node dots
    node_pass<<<1024, 256, 0, stream>>>(x, W, b, att_w, p, q, nacc, c);

    // B: 2 edges/thread
    {
        int threads = N_EDGES / 2;
        int blocks = (threads + 255) / 256;
        edge_kernel<<<blocks, 256, 0, stream>>>(e, p, q, c, nacc);
    }
    // C: 2 nodes/wave, 8 nodes/block
    {
        int blocks = (N_NODES + 7) / 8;
        final_kernel<<<blocks, 256, 0, stream>>>(x, nacc, norm_w, norm_b, out);
    }
}

// Round 6
// 162.771 us; speedup vs baseline: 2.2084x; 1.0204x over previous
//
#include <hip/hip_runtime.h>

#define N_NODES 100000
#define N_EDGES 640000
#define HIDDEN  128
#define EPS     1e-6f

typedef float v4f __attribute__((ext_vector_type(4)));  // clang-native for nontemporal builtin

// ---------------------------------------------------------------------------
// Kernel 0: u[k] = sum_j att_w[j]*W[j,k];  v[k] = sum_j att_w[128+j]*W[j,k];
//           c = att_w[0:128].b + att_w[128:256].b
// One block, 512 threads: 4 j-chunks x 128 columns, LDS tree reduce.
// ---------------------------------------------------------------------------
__global__ void precompute_uvc(const float* __restrict__ W,
                               const float* __restrict__ b,
                               const float* __restrict__ att_w,
                               float* __restrict__ u,
                               float* __restrict__ v,
                               float* __restrict__ c) {
    __shared__ float su_s[4][HIDDEN];
    __shared__ float sv_s[4][HIDDEN];
    int k     = threadIdx.x & 127;
    int chunk = threadIdx.x >> 7;   // 0..3

    float su = 0.f, sv = 0.f;
    #pragma unroll
    for (int jj = 0; jj < 32; ++jj) {
        int j = chunk * 32 + jj;
        float w = W[j * HIDDEN + k];
        su += att_w[j] * w;
        sv += att_w[HIDDEN + j] * w;
    }
    su_s[chunk][k] = su;
    sv_s[chunk][k] = sv;

    // c on the first wave, independent of the LDS reduce
    if (threadIdx.x < 64) {
        int t0 = threadIdx.x, t1 = threadIdx.x + 64;
        float t = att_w[t0] * b[t0] + att_w[HIDDEN + t0] * b[t0]
                + att_w[t1] * b[t1] + att_w[HIDDEN + t1] * b[t1];
        #pragma unroll
        for (int off = 32; off > 0; off >>= 1) t += __shfl_xor(t, off);
        if (threadIdx.x == 0) *c = t;
    }

    __syncthreads();
    if (chunk == 0) {
        u[k] = su_s[0][k] + su_s[1][k] + su_s[2][k] + su_s[3][k];
        v[k] = sv_s[0][k] + sv_s[1][k] + sv_s[2][k] + sv_s[3][k];
    }
}

// ---------------------------------------------------------------------------
// Kernel 1: p_i = u.x_i ; q_i = v.x_i + c (c folded in) ; nacc_i = 0.
// One-shot: 2 nodes/wave, float4/lane -> 1 KiB contiguous per wave.
// ---------------------------------------------------------------------------
__global__ void node_dots(const float* __restrict__ x,
                          const float* __restrict__ u,
                          const float* __restrict__ v,
                          const float* __restrict__ c,
                          float* __restrict__ p,
                          float* __restrict__ q,
                          float* __restrict__ nacc) {
    int gid  = blockIdx.x * blockDim.x + threadIdx.x;
    int wave = gid >> 6;
    int lane = threadIdx.x & 63;
    int halfw = lane >> 5;        // which node of the wave's pair
    int sub  = lane & 31;         // float4 slot within the 128-row
    int node = wave * 2 + halfw;
    if (node >= N_NODES) return;

    float4 xv = ((const float4*)(x + (size_t)node * HIDDEN))[sub];
    float4 uv = ((const float4*)u)[sub];
    float4 vv = ((const float4*)v)[sub];

    float sp = xv.x * uv.x + xv.y * uv.y + xv.z * uv.z + xv.w * uv.w;
    float sq = xv.x * vv.x + xv.y * vv.y + xv.z * vv.z + xv.w * vv.w;
    #pragma unroll
    for (int off = 16; off > 0; off >>= 1) {
        sp += __shfl_xor(sp, off);
        sq += __shfl_xor(sq, off);
    }
    if (sub == 0) {
        p[node]    = sp;
        q[node]    = sq + c[0];   // fold the constant here
        nacc[node] = 0.f;
    }
}

// ---------------------------------------------------------------------------
// Kernel 2: 2 edges/thread (one int4), a_e = exp(lrelu(p[src]+q[dst])),
// atomicAdd into nacc[dst]. p/q/nacc ~400KB each -> L2/L3 resident.
// ---------------------------------------------------------------------------
__global__ void edge_kernel(const int* __restrict__ e,
                            const float* __restrict__ p,
                            const float* __restrict__ q,
                            float* __restrict__ nacc) {
    int t = blockIdx.x * blockDim.x + threadIdx.x;
    if (t * 2 >= N_EDGES) return;
    int4 ed = ((const int4*)e)[t];       // (src0,dst0,src1,dst1)
    float s0 = p[ed.x] + q[ed.y];
    float s1 = p[ed.z] + q[ed.w];
    s0 = s0 > 0.f ? s0 : 0.2f * s0;
    s1 = s1 > 0.f ? s1 : 0.2f * s1;
    atomicAdd(&nacc[ed.y], __expf(s0));
    atomicAdd(&nacc[ed.w], __expf(s1));
}

// ---------------------------------------------------------------------------
// Kernel 3: y = relu(x/n') + x ; out = norm_w * y * rsqrt(mean(y^2)+eps) + norm_b
// 2 nodes/wave, float4/lane; nontemporal store for write-once out.
// ---------------------------------------------------------------------------
__global__ void final_kernel(const float* __restrict__ x,
                             const float* __restrict__ nacc,
                             const float* __restrict__ norm_w,
                             const float* __restrict__ norm_b,
                             float* __restrict__ out) {
    int gid  = blockIdx.x * blockDim.x + threadIdx.x;
    int wave = gid >> 6;
    int lane = threadIdx.x & 63;
    int halfw = lane >> 5;
    int sub  = lane & 31;
    int node = wave * 2 + halfw;
    if (node >= N_NODES) return;

    float nn = nacc[node];
    float inv_n = 1.f / (nn == 0.f ? 1.f : nn);

    float4 xv = ((const float4*)(x + (size_t)node * HIDDEN))[sub];
    float4 y;
    float h;
    h = xv.x * inv_n; h = h > 0.f ? h : 0.f; y.x = h + xv.x;
    h = xv.y * inv_n; h = h > 0.f ? h : 0.f; y.y = h + xv.y;
    h = xv.z * inv_n; h = h > 0.f ? h : 0.f; y.z = h + xv.z;
    h = xv.w * inv_n; h = h > 0.f ? h : 0.f; y.w = h + xv.w;

    float ss = y.x * y.x + y.y * y.y + y.z * y.z + y.w * y.w;
    #pragma unroll
    for (int off = 16; off > 0; off >>= 1) ss += __shfl_xor(ss, off);
    float inv_rms = rsqrtf(ss * (1.f / HIDDEN) + EPS);

    float4 wv = ((const float4*)norm_w)[sub];
    float4 bv = ((const float4*)norm_b)[sub];
    v4f ov;
    ov.x = wv.x * (y.x * inv_rms) + bv.x;
    ov.y = wv.y * (y.y * inv_rms) + bv.y;
    ov.z = wv.z * (y.z * inv_rms) + bv.z;
    ov.w = wv.w * (y.w * inv_rms) + bv.w;
    __builtin_nontemporal_store(ov, (v4f*)(out + (size_t)node * HIDDEN) + sub);
}

extern "C" void kernel_launch(void* const* d_in, const int* in_sizes, int n_in,
                              void* d_out, int out_size, void* d_ws, size_t ws_size,
                              hipStream_t stream) {
    const float* x      = (const float*)d_in[0];
    const float* W      = (const float*)d_in[1];
    const float* b      = (const float*)d_in[2];
    const float* att_w  = (const float*)d_in[3];
    const float* norm_w = (const float*)d_in[4];
    const float* norm_b = (const float*)d_in[5];
    const int*   e      = (const int*)d_in[6];
    float* out = (float*)d_out;

    // workspace layout (floats): u[128] v[128] c[1] pad | p[N] q[N] nacc[N]
    float* ws   = (float*)d_ws;
    float* u    = ws;
    float* v    = ws + 128;
    float* c    = ws + 256;
    float* p    = ws + 1024;
    float* q    = p + N_NODES;
    float* nacc = q + N_NODES;

    precompute_uvc<<<1, 512, 0, stream>>>(W, b, att_w, u, v, c);

    {   // 2 nodes/wave, 8 nodes per 256-thread block
        int blocks = (N_NODES + 7) / 8;
        node_dots<<<blocks, 256, 0, stream>>>(x, u, v, c, p, q, nacc);
    }
    {   // 2 edges/thread
        int threads = N_EDGES / 2;
        int blocks = (threads + 255) / 256;
        edge_kernel<<<blocks, 256, 0, stream>>>(e, p, q, nacc);
    }
    {
        int blocks = (N_NODES + 7) / 8;
        final_kernel<<<blocks, 256, 0, stream>>>(x, nacc, norm_w, norm_b, out);
    }
}

// Round 7
// 161.534 us; speedup vs baseline: 2.2253x; 1.0077x over previous
//
#include <hip/hip_runtime.h>

#define N_NODES 100000
#define N_EDGES 640000
#define HIDDEN  128
#define EPS     1e-6f

typedef float v4f __attribute__((ext_vector_type(4)));  // clang-native for nontemporal builtin

// ---------------------------------------------------------------------------
// Kernel 0: u[k] = sum_j att_w[j]*W[j,k];  v[k] = sum_j att_w[128+j]*W[j,k];
//           c = att_w[0:128].b + att_w[128:256].b
// One block, 1024 threads: 8 j-chunks x 128 columns (16-deep serial chain),
// LDS tree reduce.  Latency-bound; shorter chain than the 512-thread version.
// ---------------------------------------------------------------------------
__global__ void precompute_uvc(const float* __restrict__ W,
                               const float* __restrict__ b,
                               const float* __restrict__ att_w,
                               float* __restrict__ u,
                               float* __restrict__ v,
                               float* __restrict__ c) {
    __shared__ float su_s[8][HIDDEN];
    __shared__ float sv_s[8][HIDDEN];
    int k     = threadIdx.x & 127;
    int chunk = threadIdx.x >> 7;   // 0..7

    float su = 0.f, sv = 0.f;
    #pragma unroll
    for (int jj = 0; jj < 16; ++jj) {
        int j = chunk * 16 + jj;
        float w = W[j * HIDDEN + k];
        su += att_w[j] * w;
        sv += att_w[HIDDEN + j] * w;
    }
    su_s[chunk][k] = su;
    sv_s[chunk][k] = sv;

    // c on the first wave, independent of the LDS reduce
    if (threadIdx.x < 64) {
        int t0 = threadIdx.x, t1 = threadIdx.x + 64;
        float t = att_w[t0] * b[t0] + att_w[HIDDEN + t0] * b[t0]
                + att_w[t1] * b[t1] + att_w[HIDDEN + t1] * b[t1];
        #pragma unroll
        for (int off = 32; off > 0; off >>= 1) t += __shfl_xor(t, off);
        if (threadIdx.x == 0) *c = t;
    }

    __syncthreads();
    if (chunk == 0) {
        float fu = 0.f, fv = 0.f;
        #pragma unroll
        for (int i = 0; i < 8; ++i) { fu += su_s[i][k]; fv += sv_s[i][k]; }
        u[k] = fu;
        v[k] = fv;
    }
}

// ---------------------------------------------------------------------------
// Kernel 1: p_i = u.x_i ; q_i = v.x_i + c (c folded in) ; nacc_i = 0.
// One-shot: 2 nodes/wave, float4/lane -> 1 KiB contiguous per wave.
// ---------------------------------------------------------------------------
__global__ void node_dots(const float* __restrict__ x,
                          const float* __restrict__ u,
                          const float* __restrict__ v,
                          const float* __restrict__ c,
                          float* __restrict__ p,
                          float* __restrict__ q,
                          float* __restrict__ nacc) {
    int gid  = blockIdx.x * blockDim.x + threadIdx.x;
    int wave = gid >> 6;
    int lane = threadIdx.x & 63;
    int halfw = lane >> 5;        // which node of the wave's pair
    int sub  = lane & 31;         // float4 slot within the 128-row
    int node = wave * 2 + halfw;
    if (node >= N_NODES) return;

    float4 xv = ((const float4*)(x + (size_t)node * HIDDEN))[sub];
    float4 uv = ((const float4*)u)[sub];
    float4 vv = ((const float4*)v)[sub];

    float sp = xv.x * uv.x + xv.y * uv.y + xv.z * uv.z + xv.w * uv.w;
    float sq = xv.x * vv.x + xv.y * vv.y + xv.z * vv.z + xv.w * vv.w;
    #pragma unroll
    for (int off = 16; off > 0; off >>= 1) {
        sp += __shfl_xor(sp, off);
        sq += __shfl_xor(sq, off);
    }
    if (sub == 0) {
        p[node]    = sp;
        q[node]    = sq + c[0];   // fold the constant here
        nacc[node] = 0.f;
    }
}

// ---------------------------------------------------------------------------
// Kernel 2: 4 edges/thread (two int4), a_e = exp(lrelu(p[src]+q[dst])),
// atomicAdd into nacc[dst]. p/q/nacc ~400KB each -> L2/L3 resident.
// ---------------------------------------------------------------------------
__global__ void edge_kernel(const int* __restrict__ e,
                            const float* __restrict__ p,
                            const float* __restrict__ q,
                            float* __restrict__ nacc) {
    int t = blockIdx.x * blockDim.x + threadIdx.x;
    if (t * 4 >= N_EDGES) return;
    int4 e0 = ((const int4*)e)[t * 2];       // (src0,dst0,src1,dst1)
    int4 e1 = ((const int4*)e)[t * 2 + 1];   // (src2,dst2,src3,dst3)
    float s0 = p[e0.x] + q[e0.y];
    float s1 = p[e0.z] + q[e0.w];
    float s2 = p[e1.x] + q[e1.y];
    float s3 = p[e1.z] + q[e1.w];
    s0 = s0 > 0.f ? s0 : 0.2f * s0;
    s1 = s1 > 0.f ? s1 : 0.2f * s1;
    s2 = s2 > 0.f ? s2 : 0.2f * s2;
    s3 = s3 > 0.f ? s3 : 0.2f * s3;
    atomicAdd(&nacc[e0.y], __expf(s0));
    atomicAdd(&nacc[e0.w], __expf(s1));
    atomicAdd(&nacc[e1.y], __expf(s2));
    atomicAdd(&nacc[e1.w], __expf(s3));
}

// ---------------------------------------------------------------------------
// Kernel 3: y = relu(x/n') + x ; out = norm_w * y * rsqrt(mean(y^2)+eps) + norm_b
// 2 nodes/wave, float4/lane; nontemporal store for write-once out.
// ---------------------------------------------------------------------------
__global__ void final_kernel(const float* __restrict__ x,
                             const float* __restrict__ nacc,
                             const float* __restrict__ norm_w,
                             const float* __restrict__ norm_b,
                             float* __restrict__ out) {
    int gid  = blockIdx.x * blockDim.x + threadIdx.x;
    int wave = gid >> 6;
    int lane = threadIdx.x & 63;
    int halfw = lane >> 5;
    int sub  = lane & 31;
    int node = wave * 2 + halfw;
    if (node >= N_NODES) return;

    float nn = nacc[node];
    float inv_n = 1.f / (nn == 0.f ? 1.f : nn);

    float4 xv = ((const float4*)(x + (size_t)node * HIDDEN))[sub];
    float4 y;
    float h;
    h = xv.x * inv_n; h = h > 0.f ? h : 0.f; y.x = h + xv.x;
    h = xv.y * inv_n; h = h > 0.f ? h : 0.f; y.y = h + xv.y;
    h = xv.z * inv_n; h = h > 0.f ? h : 0.f; y.z = h + xv.z;
    h = xv.w * inv_n; h = h > 0.f ? h : 0.f; y.w = h + xv.w;

    float ss = y.x * y.x + y.y * y.y + y.z * y.z + y.w * y.w;
    #pragma unroll
    for (int off = 16; off > 0; off >>= 1) ss += __shfl_xor(ss, off);
    float inv_rms = rsqrtf(ss * (1.f / HIDDEN) + EPS);

    float4 wv = ((const float4*)norm_w)[sub];
    float4 bv = ((const float4*)norm_b)[sub];
    v4f ov;
    ov.x = wv.x * (y.x * inv_rms) + bv.x;
    ov.y = wv.y * (y.y * inv_rms) + bv.y;
    ov.z = wv.z * (y.z * inv_rms) + bv.z;
    ov.w = wv.w * (y.w * inv_rms) + bv.w;
    __builtin_nontemporal_store(ov, (v4f*)(out + (size_t)node * HIDDEN) + sub);
}

extern "C" void kernel_launch(void* const* d_in, const int* in_sizes, int n_in,
                              void* d_out, int out_size, void* d_ws, size_t ws_size,
                              hipStream_t stream) {
    const float* x      = (const float*)d_in[0];
    const float* W      = (const float*)d_in[1];
    const float* b      = (const float*)d_in[2];
    const float* att_w  = (const float*)d_in[3];
    const float* norm_w = (const float*)d_in[4];
    const float* norm_b = (const float*)d_in[5];
    const int*   e      = (const int*)d_in[6];
    float* out = (float*)d_out;

    // workspace layout (floats): u[128] v[128] c[1] pad | p[N] q[N] nacc[N]
    float* ws   = (float*)d_ws;
    float* u    = ws;
    float* v    = ws + 128;
    float* c    = ws + 256;
    float* p    = ws + 1024;
    float* q    = p + N_NODES;
    float* nacc = q + N_NODES;

    precompute_uvc<<<1, 1024, 0, stream>>>(W, b, att_w, u, v, c);

    {   // 2 nodes/wave, 8 nodes per 256-thread block
        int blocks = (N_NODES + 7) / 8;
        node_dots<<<blocks, 256, 0, stream>>>(x, u, v, c, p, q, nacc);
    }
    {   // 4 edges/thread
        int threads = N_EDGES / 4;
        int blocks = (threads + 255) / 256;
        edge_kernel<<<blocks, 256, 0, stream>>>(e, p, q, nacc);
    }
    {
        int blocks = (N_NODES + 7) / 8;
        final_kernel<<<blocks, 256, 0, stream>>>(x, nacc, norm_w, norm_b, out);
    }
}